// Round 19
// baseline (1825.137 us; speedup 1.0000x reference)
//
// CTRNN MI355X — R19: scan -> mfma_i32_16x16x64_i8 (M-dup trick), halves issue floor; proj = R18
#include <hip/hip_runtime.h>

#define T_STEPS 1024
#define BATCH   64
#define IDIM    128
#define HDIM    512
#define ALPHA_F 0.02f
#define NLOG2E  (-1.4426950408889634f)

typedef _Float16 half2_t __attribute__((ext_vector_type(2)));
typedef _Float16 f16x8 __attribute__((ext_vector_type(8)));
typedef float f32x4 __attribute__((ext_vector_type(4)));
typedef int i32x4 __attribute__((ext_vector_type(4)));
typedef unsigned int uint32;

__device__ __forceinline__ uint32 pk2(float a, float b) {
  auto p = __builtin_amdgcn_cvt_pkrtz(a, b);
  return __builtin_bit_cast(uint32, p);
}

__device__ __forceinline__ uint32 pkq(float v0, float v1, float v2, float v3, float inv) {
  int i0 = __float2int_rn(v0 * inv), i1 = __float2int_rn(v1 * inv);
  int i2 = __float2int_rn(v2 * inv), i3 = __float2int_rn(v3 * inv);
  return (uint32)(i0 & 255) | ((uint32)(i1 & 255) << 8) |
         ((uint32)(i2 & 255) << 16) | ((uint32)(i3 & 255) << 24);
}

__device__ __forceinline__ float fast_rcp(float x) {
#if __has_builtin(__builtin_amdgcn_rcpf)
  return __builtin_amdgcn_rcpf(x);
#else
  return 1.0f / x;
#endif
}

// pack 8 f32 -> f16x8 fragment (RTZ)
__device__ __forceinline__ f16x8 pk8(float4 lo, float4 hi) {
  uint4 u = make_uint4(pk2(lo.x, lo.y), pk2(lo.z, lo.w),
                       pk2(hi.x, hi.y), pk2(hi.z, hi.w));
  return __builtin_bit_cast(f16x8, u);
}

// ---------------------------------------------------------------------------
// proj via MFMA f16 (UNCHANGED from R18): D = Win_tile x x_tile, float4 stores,
// NLOG2E folded into Win fragments.
// ---------------------------------------------------------------------------
__global__ __launch_bounds__(256) void ctrnn_proj_mfma(
    const float* __restrict__ x,    // [rows][128]
    const float* __restrict__ Win,  // [512][128]
    float* __restrict__ xp,         // [rows][512], pre-scaled by -log2e
    int rows) {
  const int lane = threadIdx.x & 63;
  const int wv   = threadIdx.x >> 6;
  const int r16  = lane & 15;
  const int kg   = lane >> 4;
  const int jbase = blockIdx.y * 256 + wv * 64;

  f16x8 bf[4][4];
#pragma unroll
  for (int jt = 0; jt < 4; ++jt) {
#pragma unroll
    for (int kb = 0; kb < 4; ++kb) {
      const float* wp = Win + (size_t)(jbase + 16 * jt + r16) * IDIM + 32 * kb + 8 * kg;
      float4 lo = *(const float4*)(wp);
      float4 hi = *(const float4*)(wp + 4);
      lo.x *= NLOG2E; lo.y *= NLOG2E; lo.z *= NLOG2E; lo.w *= NLOG2E;
      hi.x *= NLOG2E; hi.y *= NLOG2E; hi.z *= NLOG2E; hi.w *= NLOG2E;
      bf[jt][kb] = pk8(lo, hi);
    }
  }

  const int mtiles = rows >> 4;
  for (int mt = blockIdx.x; mt < mtiles; mt += gridDim.x) {
    const int mbase = mt << 4;
    f16x8 af[4];
#pragma unroll
    for (int kb = 0; kb < 4; ++kb) {
      const float* xr = x + (size_t)(mbase + r16) * IDIM + 32 * kb + 8 * kg;
      float4 lo = *(const float4*)(xr);
      float4 hi = *(const float4*)(xr + 4);
      af[kb] = pk8(lo, hi);
    }
    f32x4 acc0 = {0.f, 0.f, 0.f, 0.f};
    f32x4 acc1 = {0.f, 0.f, 0.f, 0.f};
    f32x4 acc2 = {0.f, 0.f, 0.f, 0.f};
    f32x4 acc3 = {0.f, 0.f, 0.f, 0.f};
#pragma unroll
    for (int kb = 0; kb < 4; ++kb) {
      acc0 = __builtin_amdgcn_mfma_f32_16x16x32_f16(bf[0][kb], af[kb], acc0, 0, 0, 0);
      acc1 = __builtin_amdgcn_mfma_f32_16x16x32_f16(bf[1][kb], af[kb], acc1, 0, 0, 0);
      acc2 = __builtin_amdgcn_mfma_f32_16x16x32_f16(bf[2][kb], af[kb], acc2, 0, 0, 0);
      acc3 = __builtin_amdgcn_mfma_f32_16x16x32_f16(bf[3][kb], af[kb], acc3, 0, 0, 0);
    }
    float* row = xp + (size_t)(mbase + r16) * HDIM + jbase + 4 * kg;
    *(float4*)(row)      = *(float4*)&acc0;
    *(float4*)(row + 16) = *(float4*)&acc1;
    *(float4*)(row + 32) = *(float4*)&acc2;
    *(float4*)(row + 48) = *(float4*)&acc3;
  }
}

// ---------------------------------------------------------------------------
// scan via MFMA i8 (M-dup): 1 block/batch, 512 threads (8 waves, 2/SIMD).
// Wave w owns rows [64w, 64w+64) as 4 n-tiles. Weight frags wf[nt][ks]:
// A-slot map n = 64w+16nt+r16, k = 64ks+16kg+i (R18-validated input map),
// i8 per-row quantized. h (i8, LDS) broadcast into B-slot: every lane reads
// the same 16 h-bytes per kg-group -> D[n][m-dup]: lane holds z (exact i32)
// for n = 64w+16nt+4kg+q, q=0..3 -> 4 CONSECUTIVE rows: float4 xp/out,
// one b32 h-write. Epilogue on r16==0 lanes. One barrier/step (R15 proof).
// Per-SIMD issue: 2 waves x 32 mfma x ~8cy = 512 cy — half the dot4 floor.
// ---------------------------------------------------------------------------
__global__ __launch_bounds__(512)
__attribute__((amdgpu_waves_per_eu(2, 2)))
void ctrnn_scan(
    const float* __restrict__ xp,  // [ct][BATCH][HDIM], pre-scaled by -log2e
    const float* __restrict__ Wh,  // [512][512]
    const float* __restrict__ h0,  // [512]
    float* __restrict__ out,       // [T][B][H] then [B][H] final hidden
    int t0, int ct) {
  const int b = blockIdx.x;
  const int tid = threadIdx.x;
  const int w = tid >> 6;        // wave 0..7
  const int lane = tid & 63;
  const int r16 = lane & 15;
  const int kg = lane >> 4;      // 0..3
  const int nw = 64 * w;         // wave's row base
  const bool act = (r16 == 0);   // epilogue lanes (4 per wave)

  __shared__ __attribute__((aligned(16))) unsigned char hq[2][512];
  __shared__ __attribute__((aligned(16))) float rml[512];

  // ---- preamble 1: per-row absmax (rows nw+16nt+r16; cols split by kg) ----
  float rmax[4];
#pragma unroll
  for (int nt = 0; nt < 4; ++nt) {
    const float4* wr = (const float4*)(Wh + (size_t)(nw + 16 * nt + r16) * HDIM + 128 * kg);
    float mm = 0.f;
#pragma unroll
    for (int c = 0; c < 32; ++c) {
      float4 v = wr[c];
      mm = fmaxf(mm, fmaxf(fmaxf(fabsf(v.x), fabsf(v.y)), fmaxf(fabsf(v.z), fabsf(v.w))));
    }
    mm = fmaxf(mm, __shfl_xor(mm, 16));
    mm = fmaxf(mm, __shfl_xor(mm, 32));
    rmax[nt] = mm;
  }
  if (kg == 0) {
#pragma unroll
    for (int nt = 0; nt < 4; ++nt) rml[nw + 16 * nt + r16] = rmax[nt];
  }

  // ---- preamble 2: quantize weight frags wf[nt][ks] (16 i8 each) ----
  i32x4 wf[4][8];
#pragma unroll
  for (int nt = 0; nt < 4; ++nt) {
    const float inv = (rmax[nt] > 0.f) ? 127.f / rmax[nt] : 0.f;
    const float* rowp = Wh + (size_t)(nw + 16 * nt + r16) * HDIM;
#pragma unroll
    for (int ks = 0; ks < 8; ++ks) {
      const float4* p = (const float4*)(rowp + 64 * ks + 16 * kg);
      float4 v0 = p[0], v1 = p[1], v2 = p[2], v3 = p[3];
      i32x4 f;
      f[0] = (int)pkq(v0.x, v0.y, v0.z, v0.w, inv);
      f[1] = (int)pkq(v1.x, v1.y, v1.z, v1.w, inv);
      f[2] = (int)pkq(v2.x, v2.y, v2.z, v2.w, inv);
      f[3] = (int)pkq(v3.x, v3.y, v3.z, v3.w, inv);
      wf[nt][ks] = f;
    }
  }
  __syncthreads();  // rml visible

  // afac for OUTPUT rows n = nw + 16nt + 4kg + q (4 consecutive per nt)
  float4 afac[4];
#pragma unroll
  for (int nt = 0; nt < 4; ++nt) {
    float4 rv = *(const float4*)&rml[nw + 16 * nt + 4 * kg];
    const float k = NLOG2E / (127.f * 127.f);
    afac[nt] = make_float4(rv.x * k, rv.y * k, rv.z * k, rv.w * k);
  }

  // ---- initial hidden (act lanes own rows nw+16nt+4kg+q) ----
  float4 hst[4];
  if (act) {
    const float* src = (t0 == 0) ? h0 : (out + ((size_t)(t0 - 1) * BATCH + b) * HDIM);
#pragma unroll
    for (int nt = 0; nt < 4; ++nt) {
      hst[nt] = *(const float4*)(src + nw + 16 * nt + 4 * kg);
      *((uint32*)&hq[0][nw + 16 * nt + 4 * kg]) =
          pkq(hst[nt].x, hst[nt].y, hst[nt].z, hst[nt].w, 127.f);
    }
  }
  __syncthreads();

  const float* xpp = xp + (size_t)b * HDIM + nw + 4 * kg;
  float* outp = out + ((size_t)t0 * BATCH + b) * HDIM + nw + 4 * kg;
  const size_t BH = (size_t)BATCH * HDIM;

  int cur = 0;
  for (int t = 0; t < ct; ++t) {
    // xp preload (act lanes; L2 latency hides under mfma)
    float4 xw[4];
    if (act) {
#pragma unroll
      for (int nt = 0; nt < 4; ++nt) xw[nt] = *(const float4*)(xpp + 16 * nt);
    }

    // A prefetch: broadcast h-bytes per kg-group (conflict-free)
    i32x4 av[8];
#pragma unroll
    for (int ks = 0; ks < 8; ++ks)
      av[ks] = *(const i32x4*)&hq[cur][64 * ks + 16 * kg];

    i32x4 acc0 = {0, 0, 0, 0};
    i32x4 acc1 = {0, 0, 0, 0};
    i32x4 acc2 = {0, 0, 0, 0};
    i32x4 acc3 = {0, 0, 0, 0};
#pragma unroll
    for (int ks = 0; ks < 8; ++ks) {
      acc0 = __builtin_amdgcn_mfma_i32_16x16x64_i8(wf[0][ks], av[ks], acc0, 0, 0, 0);
      acc1 = __builtin_amdgcn_mfma_i32_16x16x64_i8(wf[1][ks], av[ks], acc1, 0, 0, 0);
      acc2 = __builtin_amdgcn_mfma_i32_16x16x64_i8(wf[2][ks], av[ks], acc2, 0, 0, 0);
      acc3 = __builtin_amdgcn_mfma_i32_16x16x64_i8(wf[3][ks], av[ks], acc3, 0, 0, 0);
    }

    if (act) {
#pragma unroll
      for (int nt = 0; nt < 4; ++nt) {
        const i32x4 a = (nt == 0) ? acc0 : (nt == 1) ? acc1 : (nt == 2) ? acc2 : acc3;
        const float4 af = afac[nt];
        float4 h4 = hst[nt];
        const float e0 = exp2f((float)a[0] * af.x + xw[nt].x);
        const float e1 = exp2f((float)a[1] * af.y + xw[nt].y);
        const float e2 = exp2f((float)a[2] * af.z + xw[nt].z);
        const float e3 = exp2f((float)a[3] * af.w + xw[nt].w);
        h4.x = h4.x * (1.0f - ALPHA_F) + fast_rcp(1.0f + e0) * ALPHA_F;
        h4.y = h4.y * (1.0f - ALPHA_F) + fast_rcp(1.0f + e1) * ALPHA_F;
        h4.z = h4.z * (1.0f - ALPHA_F) + fast_rcp(1.0f + e2) * ALPHA_F;
        h4.w = h4.w * (1.0f - ALPHA_F) + fast_rcp(1.0f + e3) * ALPHA_F;
        hst[nt] = h4;
        *(float4*)(outp + 16 * nt) = h4;
        *((uint32*)&hq[cur ^ 1][nw + 16 * nt + 4 * kg]) =
            pkq(h4.x, h4.y, h4.z, h4.w, 127.f);
      }
    }
    __syncthreads();
    cur ^= 1;
    xpp += BH;
    outp += BH;
  }

  if (t0 + ct == T_STEPS && act) {
    float* fin = out + (size_t)T_STEPS * BATCH * HDIM + (size_t)b * HDIM + nw + 4 * kg;
#pragma unroll
    for (int nt = 0; nt < 4; ++nt) *(float4*)(fin + 16 * nt) = hst[nt];
  }
}

// ---------------------------------------------------------------------------
extern "C" void kernel_launch(void* const* d_in, const int* in_sizes, int n_in,
                              void* d_out, int out_size, void* d_ws, size_t ws_size,
                              hipStream_t stream) {
  const float* x   = (const float*)d_in[0];
  const float* Win = (const float*)d_in[1];
  const float* Wh  = (const float*)d_in[2];
  const float* h0  = (const float*)d_in[3];
  float* out = (float*)d_out;
  float* xp  = (float*)d_ws;

  const size_t step_bytes = (size_t)BATCH * HDIM * sizeof(float);  // 128 KB
  int ct_max = (int)(ws_size / step_bytes);
  if (ct_max < 1) ct_max = 1;
  if (ct_max > T_STEPS) ct_max = T_STEPS;

  for (int t0 = 0; t0 < T_STEPS; t0 += ct_max) {
    const int ct = (T_STEPS - t0 < ct_max) ? (T_STEPS - t0) : ct_max;
    const int rows = ct * BATCH;
    const int mtiles = rows >> 4;
    const int gx = (mtiles < 1024) ? mtiles : 1024;
    hipLaunchKernelGGL(ctrnn_proj_mfma, dim3(gx, 2), dim3(256), 0, stream,
                       x + (size_t)t0 * BATCH * IDIM, Win, xp, rows);
    hipLaunchKernelGGL(ctrnn_scan, dim3(BATCH), dim3(512), 0, stream,
                       xp, Wh, h0, out, t0, ct);
  }
}

// Round 20
// 854.913 us; speedup vs baseline: 2.1349x; 2.1349x over previous
//
// CTRNN MI355X — R20: revert to R18 (best measured: 858 µs). MFMA-scan path (R19)
// is structurally dead: MFMA A/B operands must be arch-VGPRs, and block-resident
// weights = 128 dwords/thread cannot fit the 128-reg file -> scratch spill.
#include <hip/hip_runtime.h>

#define T_STEPS 1024
#define BATCH   64
#define IDIM    128
#define HDIM    512
#define ALPHA_F 0.02f
#define NLOG2E  (-1.4426950408889634f)

typedef _Float16 half2_t __attribute__((ext_vector_type(2)));
typedef _Float16 f16x8 __attribute__((ext_vector_type(8)));
typedef float f32x4 __attribute__((ext_vector_type(4)));
typedef unsigned int uint32;

__device__ __forceinline__ uint32 pk2(float a, float b) {
  auto p = __builtin_amdgcn_cvt_pkrtz(a, b);
  return __builtin_bit_cast(uint32, p);
}

__device__ __forceinline__ int dot4i8(uint32 a, uint32 b, int c) {
#if __has_builtin(__builtin_amdgcn_sdot4)
  return __builtin_amdgcn_sdot4((int)a, (int)b, c, false);
#else
  int s = c;
  s += (int)(signed char)(a)        * (int)(signed char)(b);
  s += (int)(signed char)(a >> 8)   * (int)(signed char)(b >> 8);
  s += (int)(signed char)(a >> 16)  * (int)(signed char)(b >> 16);
  s += (int)(signed char)(a >> 24)  * (int)(signed char)(b >> 24);
  return s;
#endif
}

__device__ __forceinline__ uint32 pkq(float v0, float v1, float v2, float v3, float inv) {
  int i0 = __float2int_rn(v0 * inv), i1 = __float2int_rn(v1 * inv);
  int i2 = __float2int_rn(v2 * inv), i3 = __float2int_rn(v3 * inv);
  return (uint32)(i0 & 255) | ((uint32)(i1 & 255) << 8) |
         ((uint32)(i2 & 255) << 16) | ((uint32)(i3 & 255) << 24);
}

__device__ __forceinline__ float fast_rcp(float x) {
#if __has_builtin(__builtin_amdgcn_rcpf)
  return __builtin_amdgcn_rcpf(x);
#else
  return 1.0f / x;
#endif
}

__device__ __forceinline__ int dpp_xor1(int x) {
#if __has_builtin(__builtin_amdgcn_mov_dpp)
  return __builtin_amdgcn_mov_dpp(x, 0xB1, 0xF, 0xF, true);  // quad_perm [1,0,3,2]
#else
  return __shfl_xor(x, 1);
#endif
}
__device__ __forceinline__ int dpp_xor2(int x) {
#if __has_builtin(__builtin_amdgcn_mov_dpp)
  return __builtin_amdgcn_mov_dpp(x, 0x4E, 0xF, 0xF, true);  // quad_perm [2,3,0,1]
#else
  return __shfl_xor(x, 2);
#endif
}
__device__ __forceinline__ int swz_xor4(int x) {
#if __has_builtin(__builtin_amdgcn_ds_swizzle)
  return __builtin_amdgcn_ds_swizzle(x, 0x101F);  // BitMode xor=4
#else
  return __shfl_xor(x, 4);
#endif
}
__device__ __forceinline__ float fxor1(float x) {
  return __builtin_bit_cast(float, dpp_xor1(__builtin_bit_cast(int, x)));
}
__device__ __forceinline__ float fxor2(float x) {
  return __builtin_bit_cast(float, dpp_xor2(__builtin_bit_cast(int, x)));
}
__device__ __forceinline__ float fxor4(float x) {
  return __builtin_bit_cast(float, swz_xor4(__builtin_bit_cast(int, x)));
}

// pack 8 f32 -> f16x8 fragment (RTZ)
__device__ __forceinline__ f16x8 pk8(float4 lo, float4 hi) {
  uint4 u = make_uint4(pk2(lo.x, lo.y), pk2(lo.z, lo.w),
                       pk2(hi.x, hi.y), pk2(hi.z, hi.w));
  return __builtin_bit_cast(f16x8, u);
}

// ---------------------------------------------------------------------------
// proj via MFMA f16, operand-swapped: D = Win_tile x x_tile.
// D[j_local = 4*(lane>>4)+q][m_local = lane&15] -> each lane stores 4
// CONSECUTIVE j for one m row: one float4 store per j-tile.
// NLOG2E folded into the Win fragments at load.
// ---------------------------------------------------------------------------
__global__ __launch_bounds__(256) void ctrnn_proj_mfma(
    const float* __restrict__ x,    // [rows][128]
    const float* __restrict__ Win,  // [512][128]
    float* __restrict__ xp,         // [rows][512], pre-scaled by -log2e
    int rows) {
  const int lane = threadIdx.x & 63;
  const int wv   = threadIdx.x >> 6;                 // wave 0..3
  const int r16  = lane & 15;
  const int kg   = lane >> 4;                        // 0..3
  const int jbase = blockIdx.y * 256 + wv * 64;      // wave's 64-col span

  f16x8 bf[4][4];
#pragma unroll
  for (int jt = 0; jt < 4; ++jt) {
#pragma unroll
    for (int kb = 0; kb < 4; ++kb) {
      const float* wp = Win + (size_t)(jbase + 16 * jt + r16) * IDIM + 32 * kb + 8 * kg;
      float4 lo = *(const float4*)(wp);
      float4 hi = *(const float4*)(wp + 4);
      lo.x *= NLOG2E; lo.y *= NLOG2E; lo.z *= NLOG2E; lo.w *= NLOG2E;
      hi.x *= NLOG2E; hi.y *= NLOG2E; hi.z *= NLOG2E; hi.w *= NLOG2E;
      bf[jt][kb] = pk8(lo, hi);
    }
  }

  const int mtiles = rows >> 4;
  for (int mt = blockIdx.x; mt < mtiles; mt += gridDim.x) {
    const int mbase = mt << 4;
    f16x8 af[4];
#pragma unroll
    for (int kb = 0; kb < 4; ++kb) {
      const float* xr = x + (size_t)(mbase + r16) * IDIM + 32 * kb + 8 * kg;
      float4 lo = *(const float4*)(xr);
      float4 hi = *(const float4*)(xr + 4);
      af[kb] = pk8(lo, hi);
    }
    f32x4 acc0 = {0.f, 0.f, 0.f, 0.f};
    f32x4 acc1 = {0.f, 0.f, 0.f, 0.f};
    f32x4 acc2 = {0.f, 0.f, 0.f, 0.f};
    f32x4 acc3 = {0.f, 0.f, 0.f, 0.f};
#pragma unroll
    for (int kb = 0; kb < 4; ++kb) {
      acc0 = __builtin_amdgcn_mfma_f32_16x16x32_f16(bf[0][kb], af[kb], acc0, 0, 0, 0);
      acc1 = __builtin_amdgcn_mfma_f32_16x16x32_f16(bf[1][kb], af[kb], acc1, 0, 0, 0);
      acc2 = __builtin_amdgcn_mfma_f32_16x16x32_f16(bf[2][kb], af[kb], acc2, 0, 0, 0);
      acc3 = __builtin_amdgcn_mfma_f32_16x16x32_f16(bf[3][kb], af[kb], acc3, 0, 0, 0);
    }
    float* row = xp + (size_t)(mbase + r16) * HDIM + jbase + 4 * kg;
    *(float4*)(row)      = *(float4*)&acc0;
    *(float4*)(row + 16) = *(float4*)&acc1;
    *(float4*)(row + 32) = *(float4*)&acc2;
    *(float4*)(row + 48) = *(float4*)&acc3;
  }
}

// ---------------------------------------------------------------------------
// scan kernel (R15/R18 structure): 1 block/batch, 512 threads (2 waves/SIMD).
// thread j: g = j&7 (col-eighth, 64 cols = 16 i8 dwords), o = j>>3 (rows
// 8o..8o+7); acc slot i holds row 8o+(i^g); 7-exchange DPP/swizzle reduce;
// own row lands in slot 0. h mirror: i8, row r at byte r+16*(r>>6).
// ---------------------------------------------------------------------------
__global__ __launch_bounds__(512)
__attribute__((amdgpu_waves_per_eu(2, 2)))
void ctrnn_scan(
    const float* __restrict__ xp,  // [ct][BATCH][HDIM], pre-scaled by -log2e
    const float* __restrict__ Wh,  // [512][512]
    const float* __restrict__ h0,  // [512]
    float* __restrict__ out,       // [T][B][H] then [B][H] final hidden
    int t0, int ct) {
  const int b = blockIdx.x;
  const int j = threadIdx.x;   // == output row n
  const int g = j & 7;
  const int o = j >> 3;

  __shared__ __attribute__((aligned(16))) unsigned char hq[2][640];

  // ---- pass 1: per-slot local absmax over 64 cols (slot i <-> row 8o+(i^g)) ----
  float m[8];
#pragma unroll
  for (int i = 0; i < 8; ++i) {
    const float4* wr = (const float4*)(Wh + (size_t)(8 * o + (i ^ g)) * HDIM + 64 * g);
    float mm = 0.f;
#pragma unroll
    for (int c = 0; c < 16; ++c) {
      float4 v = wr[c];
      mm = fmaxf(mm, fmaxf(fmaxf(fabsf(v.x), fabsf(v.y)), fmaxf(fabsf(v.z), fabsf(v.w))));
    }
    m[i] = mm;
  }
  {  // allreduce per row across the 8 lanes (slot-permuted partners)
    float t[8];
#pragma unroll
    for (int i = 0; i < 8; ++i) t[i] = fmaxf(m[i], fxor1(m[i ^ 1]));
#pragma unroll
    for (int i = 0; i < 8; ++i) m[i] = fmaxf(t[i], fxor2(t[i ^ 2]));
#pragma unroll
    for (int i = 0; i < 8; ++i) t[i] = fmaxf(m[i], fxor4(m[i ^ 4]));
#pragma unroll
    for (int i = 0; i < 8; ++i) m[i] = t[i];
  }

  // ---- pass 2: quantize 8 row-slices (16 dwords each) into w[128] ----
  uint32 w[128];
#pragma unroll
  for (int i = 0; i < 8; ++i) {
    const float rm = m[i];
    const float inv = (rm > 0.f) ? 127.f / rm : 0.f;
    const float4* wr = (const float4*)(Wh + (size_t)(8 * o + (i ^ g)) * HDIM + 64 * g);
#pragma unroll
    for (int c = 0; c < 16; ++c) {
      float4 v = wr[c];
      w[i * 16 + c] = pkq(v.x, v.y, v.z, v.w, inv);
    }
  }
  // afac = -log2e * fscale (own row == slot 0); xp already pre-scaled
  const float afac = m[0] * (1.f / (127.f * 127.f)) * NLOG2E;

  // ---- initial hidden: h (f32) in register, i8 mirror via b8 write ----
  float h;
  if (t0 == 0) h = h0[j];
  else h = out[((size_t)(t0 - 1) * BATCH + b) * HDIM + j];
  hq[0][j + 16 * (j >> 6)] = (unsigned char)(__float2int_rn(h * 127.f));
  __syncthreads();

  const float* xpp = xp + (size_t)b * HDIM + j;
  float* outp = out + ((size_t)t0 * BATCH + b) * HDIM + j;
  const size_t BH = (size_t)BATCH * HDIM;

  int cur = 0;
#pragma unroll 2
  for (int t = 0; t < ct; ++t) {
    const float xpw = *xpp;  // pre-scaled; L2 latency hides under dots

    const uint4* hb = (const uint4*)(&hq[cur][80 * g]);
    int a0 = 0, a1 = 0, a2 = 0, a3 = 0, a4 = 0, a5 = 0, a6 = 0, a7 = 0;
#pragma unroll
    for (int c = 0; c < 4; ++c) {
      const uint4 hv = hb[c];  // direct static index: no select chain
      a0 = dot4i8(w[0 * 16 + 4 * c + 0], hv.x, a0);
      a0 = dot4i8(w[0 * 16 + 4 * c + 1], hv.y, a0);
      a0 = dot4i8(w[0 * 16 + 4 * c + 2], hv.z, a0);
      a0 = dot4i8(w[0 * 16 + 4 * c + 3], hv.w, a0);
      a1 = dot4i8(w[1 * 16 + 4 * c + 0], hv.x, a1);
      a1 = dot4i8(w[1 * 16 + 4 * c + 1], hv.y, a1);
      a1 = dot4i8(w[1 * 16 + 4 * c + 2], hv.z, a1);
      a1 = dot4i8(w[1 * 16 + 4 * c + 3], hv.w, a1);
      a2 = dot4i8(w[2 * 16 + 4 * c + 0], hv.x, a2);
      a2 = dot4i8(w[2 * 16 + 4 * c + 1], hv.y, a2);
      a2 = dot4i8(w[2 * 16 + 4 * c + 2], hv.z, a2);
      a2 = dot4i8(w[2 * 16 + 4 * c + 3], hv.w, a2);
      a3 = dot4i8(w[3 * 16 + 4 * c + 0], hv.x, a3);
      a3 = dot4i8(w[3 * 16 + 4 * c + 1], hv.y, a3);
      a3 = dot4i8(w[3 * 16 + 4 * c + 2], hv.z, a3);
      a3 = dot4i8(w[3 * 16 + 4 * c + 3], hv.w, a3);
      a4 = dot4i8(w[4 * 16 + 4 * c + 0], hv.x, a4);
      a4 = dot4i8(w[4 * 16 + 4 * c + 1], hv.y, a4);
      a4 = dot4i8(w[4 * 16 + 4 * c + 2], hv.z, a4);
      a4 = dot4i8(w[4 * 16 + 4 * c + 3], hv.w, a4);
      a5 = dot4i8(w[5 * 16 + 4 * c + 0], hv.x, a5);
      a5 = dot4i8(w[5 * 16 + 4 * c + 1], hv.y, a5);
      a5 = dot4i8(w[5 * 16 + 4 * c + 2], hv.z, a5);
      a5 = dot4i8(w[5 * 16 + 4 * c + 3], hv.w, a5);
      a6 = dot4i8(w[6 * 16 + 4 * c + 0], hv.x, a6);
      a6 = dot4i8(w[6 * 16 + 4 * c + 1], hv.y, a6);
      a6 = dot4i8(w[6 * 16 + 4 * c + 2], hv.z, a6);
      a6 = dot4i8(w[6 * 16 + 4 * c + 3], hv.w, a6);
      a7 = dot4i8(w[7 * 16 + 4 * c + 0], hv.x, a7);
      a7 = dot4i8(w[7 * 16 + 4 * c + 1], hv.y, a7);
      a7 = dot4i8(w[7 * 16 + 4 * c + 2], hv.z, a7);
      a7 = dot4i8(w[7 * 16 + 4 * c + 3], hv.w, a7);
    }
    // 7-exchange tree (own row ends in slot 0)
    const int q0 = a0 + dpp_xor1(a1);
    const int q1 = a2 + dpp_xor1(a3);
    const int q2 = a4 + dpp_xor1(a5);
    const int q3 = a6 + dpp_xor1(a7);
    const int r0 = q0 + dpp_xor2(q1);
    const int r1 = q2 + dpp_xor2(q3);
    const int res = r0 + swz_xor4(r1);

    // sigmoid via exp2 + single-inst rcp: e = 2^(afac*res + xpw) == e^{-z}
    const float e = exp2f((float)res * afac + xpw);
    const float s = fast_rcp(1.0f + e);
    h = h * (1.0f - ALPHA_F) + s * ALPHA_F;

    // i8 mirror write (single byte) BEFORE barrier
    hq[cur ^ 1][j + 16 * (j >> 6)] = (unsigned char)(__float2int_rn(h * 127.f));
    __syncthreads();

    *outp = h;  // after barrier: issues in the shadow of next step's dots
    cur ^= 1;
    xpp += BH;
    outp += BH;
  }

  if (t0 + ct == T_STEPS) {
    out[(size_t)T_STEPS * BATCH * HDIM + (size_t)b * HDIM + j] = h;
  }
}

// ---------------------------------------------------------------------------
extern "C" void kernel_launch(void* const* d_in, const int* in_sizes, int n_in,
                              void* d_out, int out_size, void* d_ws, size_t ws_size,
                              hipStream_t stream) {
  const float* x   = (const float*)d_in[0];
  const float* Win = (const float*)d_in[1];
  const float* Wh  = (const float*)d_in[2];
  const float* h0  = (const float*)d_in[3];
  float* out = (float*)d_out;
  float* xp  = (float*)d_ws;

  const size_t step_bytes = (size_t)BATCH * HDIM * sizeof(float);  // 128 KB
  int ct_max = (int)(ws_size / step_bytes);
  if (ct_max < 1) ct_max = 1;
  if (ct_max > T_STEPS) ct_max = T_STEPS;

  for (int t0 = 0; t0 < T_STEPS; t0 += ct_max) {
    const int ct = (T_STEPS - t0 < ct_max) ? (T_STEPS - t0) : ct_max;
    const int rows = ct * BATCH;
    const int mtiles = rows >> 4;
    const int gx = (mtiles < 1024) ? mtiles : 1024;
    hipLaunchKernelGGL(ctrnn_proj_mfma, dim3(gx, 2), dim3(256), 0, stream,
                       x + (size_t)t0 * BATCH * IDIM, Win, xp, rows);
    hipLaunchKernelGGL(ctrnn_scan, dim3(BATCH), dim3(512), 0, stream,
                       xp, Wh, h0, out, t0, ct);
  }
}